// Round 2
// baseline (402.906 us; speedup 1.0000x reference)
//
#include <hip/hip_runtime.h>
#include <math.h>

#define N 8
#define DIM 64
#define H 256
#define W 256
#define K 3
#define EPS 1e-5f
#define TH 32   // rows per conv block; LDS tile = (TH+2)*W*4 = 34816 B -> 4 blocks/CU

// ---------------- Kernel 1: global average pool per (n,c) plane ----------------
__global__ __launch_bounds__(512) void gap_kernel(const float* __restrict__ x,
                                                  float* __restrict__ gap) {
    const int plane = blockIdx.x;                 // n*DIM + c, 512 planes
    const float4* p4 = (const float4*)(x + (size_t)plane * (H * W));
    const int tid = threadIdx.x;                  // 512 threads
    float s = 0.f;
    // H*W/4 = 16384 float4 per plane; 32 per thread, coalesced
    #pragma unroll 4
    for (int i = tid; i < (H * W) / 4; i += 512) {
        float4 v = p4[i];
        s += (v.x + v.y) + (v.z + v.w);
    }
    __shared__ float red[512];
    red[tid] = s;
    __syncthreads();
    for (int off = 256; off > 0; off >>= 1) {
        if (tid < off) red[tid] += red[tid + off];
        __syncthreads();
    }
    if (tid == 0) gap[plane] = red[0] * (1.0f / (H * W));
}

// ---------------- Kernel 2: fused taps + dual-strip depthwise conv ----------------
// Block: 256 threads; 64 col-groups (float4) x 4 row-slots; TH rows of one (n,c)
// plane. Computes the 6 dynamic taps in-block (6 x 64-FMA dots), then both the
// horizontal (1,K) and vertical (K,1) outputs from one LDS tile, all float4.
__global__ __launch_bounds__(256) void conv_kernel(const float* __restrict__ x,
                                                   const float* __restrict__ gap,
                                                   const float* __restrict__ wH,
                                                   const float* __restrict__ gH,
                                                   const float* __restrict__ bH,
                                                   const float* __restrict__ mH,
                                                   const float* __restrict__ vH,
                                                   const float* __restrict__ wW,
                                                   const float* __restrict__ gW,
                                                   const float* __restrict__ bW,
                                                   const float* __restrict__ mW,
                                                   const float* __restrict__ vW,
                                                   float* __restrict__ out) {
    __shared__ float tile[(TH + 2) * W];
    __shared__ float s_taps[6];                   // tH0..2, tW0..2

    const int plane = blockIdx.y;                 // n*DIM + c
    const int n = plane / DIM;
    const int c = plane % DIM;
    const int h0 = blockIdx.x * TH;
    const int tid = threadIdx.x;

    // --- taps: threads 0..5 each compute one tanh(BN(gap . w_row)) ---
    if (tid < 6) {
        const int br = tid / K;                   // 0 = H-branch, 1 = W-branch
        const int k  = tid % K;
        const int j  = c * K + k;
        const float* w = br ? wW : wH;
        const float* g = br ? gW : gH;
        const float* b = br ? bW : bH;
        const float* m = br ? mW : mH;
        const float* v = br ? vW : vH;
        const float* grow = gap + n * DIM;
        const float* wrow = w + (size_t)j * DIM;
        float acc = 0.f;
        #pragma unroll
        for (int d = 0; d < DIM; d++) acc += grow[d] * wrow[d];
        float f = (acc - m[j]) * (g[j] * rsqrtf(v[j] + EPS)) + b[j];
        s_taps[tid] = tanhf(f);
    }

    // --- stage TH+2 rows (h0-1 .. h0+TH) as float4, reflect at plane edges ---
    const float4* xp4 = (const float4*)(x + (size_t)plane * (H * W));
    float4* t4 = (float4*)tile;
    for (int idx = tid; idx < (TH + 2) * W / 4; idx += 256) {
        const int row = idx >> 6;                 // 0..33
        int hh = h0 - 1 + row;
        if (hh < 0) hh = 1;                       // -1 -> 1 (reflect, edge excluded)
        else if (hh >= H) hh = 2 * H - 2 - hh;    //  H -> H-2
        t4[idx] = xp4[hh * (W / 4) + (idx & 63)];
    }
    __syncthreads();

    const float tH0 = s_taps[0], tH1 = s_taps[1], tH2 = s_taps[2];
    const float tW0 = s_taps[3], tW1 = s_taps[4], tW2 = s_taps[5];

    const int tx = tid & 63;                      // col group: cols 4tx..4tx+3
    const int ty = tid >> 6;                      // 0..3 row slot

    // Output: (N, 2*DIM, H, W); branch0 channels [0,DIM), branch1 [DIM,2*DIM)
    float4* o1 = (float4*)out + ((size_t)(n * 2 * DIM + c) * H + h0) * (W / 4);
    float4* o2 = (float4*)out + ((size_t)(n * 2 * DIM + DIM + c) * H + h0) * (W / 4);

    #pragma unroll
    for (int r = 0; r < TH / 4; r++) {
        const int row = r * 4 + ty;               // 0..31 within tile
        const float* rc = tile + (row + 1) * W;   // center row
        const float4 cc = ((const float4*)rc)[tx];
        const float4 up = ((const float4*)(tile + row * W))[tx];
        const float4 dn = ((const float4*)(tile + (row + 2) * W))[tx];
        // W-reflect folds into registers at the edges
        const float lf = (tx == 0)  ? cc.y : rc[4 * tx - 1];
        const float rt = (tx == 63) ? cc.z : rc[4 * tx + 4];

        float4 r1, r2;
        r1.x = lf   * tH0 + cc.x * tH1 + cc.y * tH2;
        r1.y = cc.x * tH0 + cc.y * tH1 + cc.z * tH2;
        r1.z = cc.y * tH0 + cc.z * tH1 + cc.w * tH2;
        r1.w = cc.z * tH0 + cc.w * tH1 + rt   * tH2;

        r2.x = up.x * tW0 + cc.x * tW1 + dn.x * tW2;
        r2.y = up.y * tW0 + cc.y * tW1 + dn.y * tW2;
        r2.z = up.z * tW0 + cc.z * tW1 + dn.z * tW2;
        r2.w = up.w * tW0 + cc.w * tW1 + dn.w * tW2;

        o1[row * (W / 4) + tx] = r1;
        o2[row * (W / 4) + tx] = r2;
    }
}

extern "C" void kernel_launch(void* const* d_in, const int* in_sizes, int n_in,
                              void* d_out, int out_size, void* d_ws, size_t ws_size,
                              hipStream_t stream) {
    const float* x  = (const float*)d_in[0];
    const float* wH = (const float*)d_in[1];
    const float* gH = (const float*)d_in[2];
    const float* bH = (const float*)d_in[3];
    const float* mH = (const float*)d_in[4];
    const float* vH = (const float*)d_in[5];
    const float* wW = (const float*)d_in[6];
    const float* gW = (const float*)d_in[7];
    const float* bW = (const float*)d_in[8];
    const float* mW = (const float*)d_in[9];
    const float* vW = (const float*)d_in[10];
    float* out = (float*)d_out;

    float* gap = (float*)d_ws;                    // N*DIM floats

    gap_kernel<<<N * DIM, 512, 0, stream>>>(x, gap);

    dim3 grid(H / TH, N * DIM);
    conv_kernel<<<grid, 256, 0, stream>>>(x, gap, wH, gH, bH, mH, vH,
                                          wW, gW, bW, mW, vW, out);
}

// Round 4
// 388.746 us; speedup vs baseline: 1.0364x; 1.0364x over previous
//
#include <hip/hip_runtime.h>
#include <math.h>

#define N 8
#define DIM 64
#define H 256
#define W 256
#define K 3
#define EPS 1e-5f
#define RT 16   // output rows per conv block (4 row-slots x 4 rows each)

typedef float f4 __attribute__((ext_vector_type(4)));   // native vec, nt-store OK

// ---------------- Kernel 1: global average pool per (n,c) plane ----------------
__global__ __launch_bounds__(512) void gap_kernel(const float* __restrict__ x,
                                                  float* __restrict__ gap) {
    const int plane = blockIdx.x;                 // n*DIM + c, 512 planes
    const f4* p4 = (const f4*)(x + (size_t)plane * (H * W));
    const int tid = threadIdx.x;                  // 512 threads
    float s = 0.f;
    #pragma unroll 4
    for (int i = tid; i < (H * W) / 4; i += 512) {
        f4 v = p4[i];
        s += (v.x + v.y) + (v.z + v.w);
    }
    __shared__ float red[512];
    red[tid] = s;
    __syncthreads();
    for (int off = 256; off > 0; off >>= 1) {
        if (tid < off) red[tid] += red[tid + off];
        __syncthreads();
    }
    if (tid == 0) gap[plane] = red[0] * (1.0f / (H * W));
}

// ---------------- Kernel 2: fused taps + dual-strip conv, register-resident ----
// 256 threads: tx = float4 column (0..63), ty = 4-row slot (0..3).
// Each thread keeps 6 rows (4 outputs + vertical halo) in registers; horizontal
// neighbors come from intra-wave shuffles. No x tile in LDS; one tiny sync for
// the 6 dynamic taps. Nontemporal float4 stores keep x L3-resident.
__global__ __launch_bounds__(256) void conv_kernel(const float* __restrict__ x,
                                                   const float* __restrict__ gap,
                                                   const float* __restrict__ wH,
                                                   const float* __restrict__ gH,
                                                   const float* __restrict__ bH,
                                                   const float* __restrict__ mH,
                                                   const float* __restrict__ vH,
                                                   const float* __restrict__ wW,
                                                   const float* __restrict__ gW,
                                                   const float* __restrict__ bW,
                                                   const float* __restrict__ mW,
                                                   const float* __restrict__ vW,
                                                   float* __restrict__ out) {
    __shared__ float s_taps[6];                   // tH0..2, tW0..2

    const int plane = blockIdx.y;                 // n*DIM + c
    const int n = plane / DIM;
    const int c = plane % DIM;
    const int tid = threadIdx.x;
    const int tx = tid & 63;                      // float4 col, also lane id
    const int ty = tid >> 6;                      // 0..3 row slot
    const int r0 = blockIdx.x * RT + ty * 4;      // first output row

    // --- taps: threads 0..5 each compute one tanh(BN(gap . w_row)) ---
    if (tid < 6) {
        const int br = tid / K;                   // 0 = H-branch, 1 = W-branch
        const int k  = tid % K;
        const int j  = c * K + k;
        const float* w = br ? wW : wH;
        const float* g = br ? gW : gH;
        const float* b = br ? bW : bH;
        const float* m = br ? mW : mH;
        const float* v = br ? vW : vH;
        const float* grow = gap + n * DIM;
        const float* wrow = w + (size_t)j * DIM;
        float acc = 0.f;
        #pragma unroll
        for (int d = 0; d < DIM; d++) acc += grow[d] * wrow[d];
        float f = (acc - m[j]) * (g[j] * rsqrtf(v[j] + EPS)) + b[j];
        s_taps[tid] = tanhf(f);
    }

    // --- load 6 rows (r0-1 .. r0+4) as float4, reflect at plane edges ---
    const f4* xp4 = (const f4*)(x + (size_t)plane * (H * W));
    f4 v[6];
    #pragma unroll
    for (int j = 0; j < 6; j++) {
        int hh = r0 - 1 + j;
        if (hh < 0) hh = 1;                       // -1 -> 1 (reflect, edge excluded)
        else if (hh >= H) hh = 2 * H - 2 - hh;    //  H -> H-2
        v[j] = xp4[hh * (W / 4) + tx];
    }
    __syncthreads();

    const float tH0 = s_taps[0], tH1 = s_taps[1], tH2 = s_taps[2];
    const float tW0 = s_taps[3], tW1 = s_taps[4], tW2 = s_taps[5];

    // Output: (N, 2*DIM, H, W); branch0 channels [0,DIM), branch1 [DIM,2*DIM)
    f4* o1 = (f4*)out + ((size_t)(n * 2 * DIM + c) * H + r0) * (W / 4) + tx;
    f4* o2 = (f4*)out + ((size_t)(n * 2 * DIM + DIM + c) * H + r0) * (W / 4) + tx;

    #pragma unroll
    for (int i = 0; i < 4; i++) {
        const f4 up = v[i];
        const f4 cc = v[i + 1];
        const f4 dn = v[i + 2];
        // W-neighbors via intra-wave shuffle (lane tx-1 holds col 4tx-1 in .w)
        float lf = __shfl_up(cc.w, 1, 64);
        float rt = __shfl_down(cc.x, 1, 64);
        if (tx == 0)  lf = cc.y;                  // reflect col -1 -> 1
        if (tx == 63) rt = cc.z;                  // reflect col 256 -> 254

        f4 r1, r2;
        r1.x = lf   * tH0 + cc.x * tH1 + cc.y * tH2;
        r1.y = cc.x * tH0 + cc.y * tH1 + cc.z * tH2;
        r1.z = cc.y * tH0 + cc.z * tH1 + cc.w * tH2;
        r1.w = cc.z * tH0 + cc.w * tH1 + rt   * tH2;

        r2.x = up.x * tW0 + cc.x * tW1 + dn.x * tW2;
        r2.y = up.y * tW0 + cc.y * tW1 + dn.y * tW2;
        r2.z = up.z * tW0 + cc.z * tW1 + dn.z * tW2;
        r2.w = up.w * tW0 + cc.w * tW1 + dn.w * tW2;

        __builtin_nontemporal_store(r1, o1 + i * (W / 4));
        __builtin_nontemporal_store(r2, o2 + i * (W / 4));
    }
}

extern "C" void kernel_launch(void* const* d_in, const int* in_sizes, int n_in,
                              void* d_out, int out_size, void* d_ws, size_t ws_size,
                              hipStream_t stream) {
    const float* x  = (const float*)d_in[0];
    const float* wH = (const float*)d_in[1];
    const float* gH = (const float*)d_in[2];
    const float* bH = (const float*)d_in[3];
    const float* mH = (const float*)d_in[4];
    const float* vH = (const float*)d_in[5];
    const float* wW = (const float*)d_in[6];
    const float* gW = (const float*)d_in[7];
    const float* bW = (const float*)d_in[8];
    const float* mW = (const float*)d_in[9];
    const float* vW = (const float*)d_in[10];
    float* out = (float*)d_out;

    float* gap = (float*)d_ws;                    // N*DIM floats

    gap_kernel<<<N * DIM, 512, 0, stream>>>(x, gap);

    dim3 grid(H / RT, N * DIM);
    conv_kernel<<<grid, 256, 0, stream>>>(x, gap, wH, gH, bH, mH, vH,
                                          wW, gW, bW, mW, vW, out);
}